// Round 2
// baseline (861.945 us; speedup 1.0000x reference)
//
#include <hip/hip_runtime.h>

// Scatter-add: out[t] += msg[e] for t = edge_index[1][e].
// msg: (E, 32) float32, edge_index: (2, E) int (row-major: row0 = src, row1 = tgt),
// out: (N, 32) float32, N = 100000, E = 1,600,000.

#define FEAT 32

__global__ void scatter_add_kernel(const float4* __restrict__ msg4,
                                   const int* __restrict__ tgt,
                                   float* __restrict__ out,
                                   int num_edges) {
    int i = blockIdx.x * blockDim.x + threadIdx.x;   // one thread = one float4 (4 feats)
    int total = num_edges * (FEAT / 4);              // 8 quads per edge
    if (i >= total) return;
    int e = i >> 3;          // edge index
    int q = i & 7;           // which quad within the 32-feature row
    float4 m = msg4[i];      // coalesced: consecutive lanes -> consecutive 16B
    int t = tgt[e];          // 8 lanes broadcast-read the same target
    float* dst = out + (size_t)t * FEAT + q * 4;
    atomicAdd(dst + 0, m.x);
    atomicAdd(dst + 1, m.y);
    atomicAdd(dst + 2, m.z);
    atomicAdd(dst + 3, m.w);
}

extern "C" void kernel_launch(void* const* d_in, const int* in_sizes, int n_in,
                              void* d_out, int out_size, void* d_ws, size_t ws_size,
                              hipStream_t stream) {
    const float* msg = (const float*)d_in[0];
    const int* edge_index = (const int*)d_in[1];
    // d_in[2] = num_nodes scalar on device; problem is fixed-shape, use out_size.
    int num_edges = in_sizes[0] / FEAT;              // 1,600,000
    const int* tgt = edge_index + num_edges;         // row 1 of (2, E)

    // Harness poisons d_out with 0xAA before every timed launch — zero it.
    hipMemsetAsync(d_out, 0, (size_t)out_size * sizeof(float), stream);

    int total = num_edges * (FEAT / 4);              // 12.8M threads
    int block = 256;
    int grid = (total + block - 1) / block;
    scatter_add_kernel<<<grid, block, 0, stream>>>(
        (const float4*)msg, tgt, (float*)d_out, num_edges);
}

// Round 3
// 593.250 us; speedup vs baseline: 1.4529x; 1.4529x over previous
//
#include <hip/hip_runtime.h>

// out[t] += msg[e] for t = edge_index[1][e], via on-device counting sort (CSR)
// then atomic-free gather. msg: (E,32) f32; edge_index: (2,E) int32 (harness
// converts int64->int32); out: (N,32) f32. E=1.6M, N=100K.

#define FEAT 32
#define SCAN_BS 1024

// ---- pass 1: histogram of target nodes --------------------------------------
__global__ void hist_kernel(const int* __restrict__ tgt, int* __restrict__ cnt, int E) {
    int e = blockIdx.x * blockDim.x + threadIdx.x;
    if (e < E) atomicAdd(&cnt[tgt[e]], 1);
}

// ---- pass 2a: per-block inclusive scan of counts ----------------------------
__global__ void scan_block_kernel(const int* __restrict__ cnt, int* __restrict__ off,
                                  int* __restrict__ psum, int N) {
    __shared__ int s[SCAN_BS];
    int i = blockIdx.x * SCAN_BS + threadIdx.x;
    s[threadIdx.x] = (i < N) ? cnt[i] : 0;
    __syncthreads();
    for (int d = 1; d < SCAN_BS; d <<= 1) {            // Hillis-Steele, 10 stages
        int t = (threadIdx.x >= d) ? s[threadIdx.x - d] : 0;
        __syncthreads();
        s[threadIdx.x] += t;
        __syncthreads();
    }
    if (i < N) off[i + 1] = s[threadIdx.x];            // local inclusive scan
    if (threadIdx.x == SCAN_BS - 1) psum[blockIdx.x] = s[SCAN_BS - 1];
}

// ---- pass 2b: serial exclusive scan of the ~98 block totals -----------------
__global__ void scan_partials_kernel(int* psum, int nb) {
    int run = 0;
    for (int b = 0; b < nb; ++b) { int t = psum[b]; psum[b] = run; run += t; }
}

// ---- pass 2c: add block prefix; repurpose cnt[] as the scatter cursor -------
__global__ void finalize_offsets_kernel(int* __restrict__ off, int* __restrict__ cnt,
                                        const int* __restrict__ psum, int N) {
    int i = blockIdx.x * SCAN_BS + threadIdx.x;
    if (i == 0) off[0] = 0;
    if (i < N) {
        int end = off[i + 1] + psum[blockIdx.x];       // global inclusive scan
        off[i + 1] = end;
        cnt[i] = end - cnt[i];                         // cursor = start offset
    }
}

// ---- pass 3: bin edge ids by target -----------------------------------------
__global__ void scatter_ids_kernel(const int* __restrict__ tgt, int* __restrict__ cur,
                                   int* __restrict__ eid, int E) {
    int e = blockIdx.x * blockDim.x + threadIdx.x;
    if (e < E) {
        int pos = atomicAdd(&cur[tgt[e]], 1);
        eid[pos] = e;
    }
}

// ---- pass 4: atomic-free gather; half-wave (32 lanes = 32 feats) per node ---
__global__ void gather_sum_kernel(const float* __restrict__ msg, const int* __restrict__ off,
                                  const int* __restrict__ eid, float* __restrict__ out,
                                  int total) {
    int i = blockIdx.x * blockDim.x + threadIdx.x;     // i = n*32 + f
    if (i >= total) return;
    int n = i >> 5, f = i & 31;
    int start = off[n], end = off[n + 1];
    float acc = 0.f;
    for (int j = start; j < end; ++j) {
        int e = eid[j];                                // broadcast within half-wave
        acc += msg[(size_t)e * FEAT + f];              // 128 B coalesced row read
    }
    out[i] = acc;                                      // written exactly once
}

// ---- fallback: round-2 atomic scatter (if ws too small) ---------------------
__global__ void scatter_add_kernel(const float4* __restrict__ msg4,
                                   const int* __restrict__ tgt,
                                   float* __restrict__ out, int num_edges) {
    int i = blockIdx.x * blockDim.x + threadIdx.x;
    if (i >= num_edges * (FEAT / 4)) return;
    int e = i >> 3, q = i & 7;
    float4 m = msg4[i];
    int t = tgt[e];
    float* dst = out + (size_t)t * FEAT + q * 4;
    atomicAdd(dst + 0, m.x); atomicAdd(dst + 1, m.y);
    atomicAdd(dst + 2, m.z); atomicAdd(dst + 3, m.w);
}

extern "C" void kernel_launch(void* const* d_in, const int* in_sizes, int n_in,
                              void* d_out, int out_size, void* d_ws, size_t ws_size,
                              hipStream_t stream) {
    const float* msg = (const float*)d_in[0];
    const int* edge_index = (const int*)d_in[1];
    int E = in_sizes[0] / FEAT;                        // 1,600,000
    int N = out_size / FEAT;                           // 100,000
    const int* tgt = edge_index + E;                   // row 1 of (2,E)

    int nb = (N + SCAN_BS - 1) / SCAN_BS;              // ~98 scan blocks
    // ws layout (ints): cnt[N] | off[N+1] | psum[nb] | eid[E]
    size_t need = ((size_t)N + (N + 1) + nb + E) * sizeof(int);
    if (ws_size < need) {                              // fallback: atomic scatter
        hipMemsetAsync(d_out, 0, (size_t)out_size * sizeof(float), stream);
        int total = E * (FEAT / 4);
        scatter_add_kernel<<<(total + 255) / 256, 256, 0, stream>>>(
            (const float4*)msg, tgt, (float*)d_out, E);
        return;
    }

    int* cnt  = (int*)d_ws;
    int* off  = cnt + N;
    int* psum = off + N + 1;
    int* eid  = psum + nb;

    hipMemsetAsync(cnt, 0, (size_t)N * sizeof(int), stream);   // ws is poisoned 0xAA

    hist_kernel<<<(E + 255) / 256, 256, 0, stream>>>(tgt, cnt, E);
    scan_block_kernel<<<nb, SCAN_BS, 0, stream>>>(cnt, off, psum, N);
    scan_partials_kernel<<<1, 1, 0, stream>>>(psum, nb);
    finalize_offsets_kernel<<<nb, SCAN_BS, 0, stream>>>(off, cnt, psum, N);
    scatter_ids_kernel<<<(E + 255) / 256, 256, 0, stream>>>(tgt, cnt, eid, E);
    gather_sum_kernel<<<(out_size + 255) / 256, 256, 0, stream>>>(
        msg, off, eid, (float*)d_out, out_size);
}

// Round 4
// 501.651 us; speedup vs baseline: 1.7182x; 1.1826x over previous
//
#include <hip/hip_runtime.h>

// out[t] += msg[e] for t = edge_index[1][e], via on-device counting sort (CSR)
// then atomic-free gather. msg: (E,32) f32; edge_index: (2,E) int32; out: (N,32) f32.

#define FEAT 32
#define SCAN_BS 1024
#define PART_BS 256
#define UNROLL 8

// ---- pass 1: histogram of target nodes --------------------------------------
__global__ void hist_kernel(const int* __restrict__ tgt, int* __restrict__ cnt, int E) {
    int e = blockIdx.x * blockDim.x + threadIdx.x;
    if (e < E) atomicAdd(&cnt[tgt[e]], 1);
}

// ---- pass 2a: per-block inclusive scan of counts ----------------------------
__global__ void scan_block_kernel(const int* __restrict__ cnt, int* __restrict__ off,
                                  int* __restrict__ psum, int N) {
    __shared__ int s[SCAN_BS];
    int i = blockIdx.x * SCAN_BS + threadIdx.x;
    s[threadIdx.x] = (i < N) ? cnt[i] : 0;
    __syncthreads();
    for (int d = 1; d < SCAN_BS; d <<= 1) {
        int t = (threadIdx.x >= d) ? s[threadIdx.x - d] : 0;
        __syncthreads();
        s[threadIdx.x] += t;
        __syncthreads();
    }
    if (i < N) off[i + 1] = s[threadIdx.x];
    if (threadIdx.x == SCAN_BS - 1) psum[blockIdx.x] = s[SCAN_BS - 1];
}

// ---- pass 2b: block-parallel exclusive scan of the block totals -------------
__global__ void scan_partials_kernel(int* __restrict__ psum, int nb) {
    __shared__ int s[PART_BS];
    int run = 0;
    for (int base = 0; base < nb; base += PART_BS) {
        int i = base + threadIdx.x;
        int v = (i < nb) ? psum[i] : 0;
        s[threadIdx.x] = v;
        __syncthreads();
        for (int d = 1; d < PART_BS; d <<= 1) {
            int t = (threadIdx.x >= d) ? s[threadIdx.x - d] : 0;
            __syncthreads();
            s[threadIdx.x] += t;
            __syncthreads();
        }
        if (i < nb) psum[i] = run + s[threadIdx.x] - v;   // exclusive
        run += s[PART_BS - 1];
        __syncthreads();                                   // protect s before next chunk
    }
}

// ---- pass 2c: add block prefix; repurpose cnt[] as the scatter cursor -------
__global__ void finalize_offsets_kernel(int* __restrict__ off, int* __restrict__ cnt,
                                        const int* __restrict__ psum, int N) {
    int i = blockIdx.x * SCAN_BS + threadIdx.x;
    if (i == 0) off[0] = 0;
    if (i < N) {
        int end = off[i + 1] + psum[blockIdx.x];
        off[i + 1] = end;
        cnt[i] = end - cnt[i];                             // cursor = start offset
    }
}

// ---- pass 3: bin edge ids by target -----------------------------------------
__global__ void scatter_ids_kernel(const int* __restrict__ tgt, int* __restrict__ cur,
                                   int* __restrict__ eid, int E) {
    int e = blockIdx.x * blockDim.x + threadIdx.x;
    if (e < E) {
        int pos = atomicAdd(&cur[tgt[e]], 1);
        eid[pos] = e;
    }
}

// ---- pass 4: gather; half-wave (32 lanes = 32 feats) per node, 8-deep MLP ---
__global__ void gather_sum_kernel(const float* __restrict__ msg, const int* __restrict__ off,
                                  const int* __restrict__ eid, float* __restrict__ out,
                                  int total) {
    int i = blockIdx.x * blockDim.x + threadIdx.x;         // i = n*32 + f
    if (i >= total) return;
    int n = i >> 5, f = i & 31;
    int start = off[n], end = off[n + 1];
    float acc[UNROLL];
#pragma unroll
    for (int u = 0; u < UNROLL; ++u) acc[u] = 0.f;
    for (int j = start; j < end; j += UNROLL) {
        // Always issue UNROLL independent loads (clamped dup at end-1, L1-hit);
        // predicate the accumulate. No serial tail, 8 msg rows in flight.
#pragma unroll
        for (int u = 0; u < UNROLL; ++u) {
            int jj = j + u;
            int e = eid[jj < end ? jj : end - 1];
            float m = msg[(size_t)e * FEAT + f];
            acc[u] += (jj < end) ? m : 0.f;
        }
    }
    float r = 0.f;
#pragma unroll
    for (int u = 0; u < UNROLL; ++u) r += acc[u];
    out[i] = r;                                            // written exactly once
}

extern "C" void kernel_launch(void* const* d_in, const int* in_sizes, int n_in,
                              void* d_out, int out_size, void* d_ws, size_t ws_size,
                              hipStream_t stream) {
    const float* msg = (const float*)d_in[0];
    const int* edge_index = (const int*)d_in[1];
    int E = in_sizes[0] / FEAT;                            // 1,600,000
    int N = out_size / FEAT;                               // 100,000
    const int* tgt = edge_index + E;                       // row 1 of (2,E)

    int nb = (N + SCAN_BS - 1) / SCAN_BS;                  // ~98 scan blocks
    // ws layout (ints): cnt[N] | off[N+1] | psum[nb] | eid[E]
    int* cnt  = (int*)d_ws;
    int* off  = cnt + N;
    int* psum = off + N + 1;
    int* eid  = psum + nb;

    hipMemsetAsync(cnt, 0, (size_t)N * sizeof(int), stream);   // ws is poisoned 0xAA

    hist_kernel<<<(E + 255) / 256, 256, 0, stream>>>(tgt, cnt, E);
    scan_block_kernel<<<nb, SCAN_BS, 0, stream>>>(cnt, off, psum, N);
    scan_partials_kernel<<<1, PART_BS, 0, stream>>>(psum, nb);
    finalize_offsets_kernel<<<nb, SCAN_BS, 0, stream>>>(off, cnt, psum, N);
    scatter_ids_kernel<<<(E + 255) / 256, 256, 0, stream>>>(tgt, cnt, eid, E);
    gather_sum_kernel<<<(out_size + 255) / 256, 256, 0, stream>>>(
        msg, off, eid, (float*)d_out, out_size);
}